// Round 21
// baseline (114.758 us; speedup 1.0000x reference)
//
#include <hip/hip_runtime.h>
#include <hip/hip_bf16.h>
#include <stdint.h>

typedef __bf16 bf16;
typedef __bf16 bf16x8 __attribute__((ext_vector_type(8)));
typedef float f32x4 __attribute__((ext_vector_type(4)));
typedef float f32x16 __attribute__((ext_vector_type(16)));

#define B_ 2
#define S_ 2048
#define D_ 1024
#define H_ 16
#define DK 64
#define M_ 4096

__device__ __forceinline__ void gload_lds16(const void* g, void* l) {
  __builtin_amdgcn_global_load_lds(
      (const __attribute__((address_space(1))) uint32_t*)(uintptr_t)g,
      (__attribute__((address_space(3))) uint32_t*)(uintptr_t)l, 16, 0, 0);
}

__device__ __forceinline__ uint32_t pkbf(float a, float b) {
  union { uint32_t u; struct { bf16 x, y; } s; } r;
  r.s.x = (bf16)a; r.s.y = (bf16)b;
  return r.u;
}

// ---------------- f32 -> bf16 convert (all 5 tensors, one launch) ----------------
struct alignas(8) B4s { bf16 a, b, c, d; };

__global__ __launch_bounds__(256) void cvt_all_kernel(
    const float* __restrict__ x, const float* __restrict__ wq, const float* __restrict__ wk,
    const float* __restrict__ wv, const float* __restrict__ wo,
    bf16* __restrict__ xb, bf16* __restrict__ wqb, bf16* __restrict__ wkb,
    bf16* __restrict__ wvb, bf16* __restrict__ wob) {
  int i = blockIdx.x * 256 + threadIdx.x;  // float4 index
  const float* src;
  bf16* dst;
  int off;
  if (i < 1048576) { src = x; dst = xb; off = i; }
  else if (i < 1310720) { src = wq; dst = wqb; off = i - 1048576; }
  else if (i < 1572864) { src = wk; dst = wkb; off = i - 1310720; }
  else if (i < 1835008) { src = wv; dst = wvb; off = i - 1572864; }
  else { src = wo; dst = wob; off = i - 1835008; }
  float4 v = reinterpret_cast<const float4*>(src)[off];
  B4s o{(bf16)v.x, (bf16)v.y, (bf16)v.z, (bf16)v.w};
  reinterpret_cast<B4s*>(dst)[off] = o;
}

// ---------------- GEMM: C[m][n] = sum_k A[m][k] * W[n][k] ----------------
// Pipelined port of the proven attn loop: BK=32, TRIPLE-buffered LDS (48/24 KB),
// depth-2 global_load_lds prefetch, ONE barrier/iter with COUNTED vmcnt (never 0
// mid-loop; T3/T4). 32x32x16 MFMA core + (row&3)*8 XOR swizzle (read 4-way worst).
// MODE 0: 128x128 tiles, 768 blocks (3/CU). MODE 1: 64x64 tiles, 1024 blocks.
template <int MODE>
__global__ __launch_bounds__(256, 3) void gemm_kernel(
    const bf16* __restrict__ A,
    const bf16* __restrict__ W0, const bf16* __restrict__ W1, const bf16* __restrict__ W2,
    bf16* __restrict__ q_out, bf16* __restrict__ k_out, bf16* __restrict__ v_out,
    float* __restrict__ c_out) {
  constexpr int BK = 32;
  constexpr int BM = (MODE == 0) ? 128 : 64;
  constexpr int BNR = (MODE == 0) ? 128 : 64;
  constexpr int AM = (MODE == 0) ? 2 : 1;
  constexpr int BN = (MODE == 0) ? 2 : 1;
  constexpr int NT = (MODE == 0) ? 24 : 16;
  constexpr int PERX = (MODE == 0) ? 96 : 128;
  constexpr int AE = BM * BK;
  constexpr int BE = BNR * BK;
  constexpr int ACALLS = BM / 64;   // gloads per wave per stage (A)
  constexpr int BCALLS = BNR / 64;
  constexpr int INF = ACALLS + BCALLS;  // per-wave loads left in flight at fence
  __shared__ bf16 smem[3 * (AE + BE)];
  bf16* Ab3 = smem;
  bf16* Bb3 = smem + 3 * AE;
  const int tid = threadIdx.x;
  const int w = tid >> 6, l = tid & 63;
  const int l31 = l & 31, hh = l >> 5;
  const int lin = (blockIdx.x & 7) * PERX + (blockIdx.x >> 3);
  const int m0 = (lin / NT) * BM;
  const int nt = lin % NT;
  const bf16* W;
  int n0;
  const int rt = (MODE == 0) ? (nt >> 3) : 0;
  if (MODE == 0) {
    W = rt == 0 ? W0 : (rt == 1 ? W1 : W2);
    n0 = (nt & 7) * 128;
  } else {
    W = W0;
    n0 = nt * 64;
  }
  const int K = 1024;
  const int wm = (MODE == 0) ? (w >> 1) * 64 : (w & 1) * 32;
  const int wn = (MODE == 0) ? (w & 1) * 64 : (w >> 1) * 32;
  // staging: wave w, call c covers rows c*64 + w*16 + (l>>2); 16B at pre-swizzled col
  const int sr = l >> 2;
  const int sc = ((l & 3) * 8) ^ ((sr & 3) * 8);
  const int rswz = (l31 & 3) * 8;  // read-side XOR (frag row&3 == l31&3)

  auto stage = [&](int kt, int buf) {
    const bf16* Ag = A + (size_t)m0 * K + kt * BK;
    const bf16* Bg = W + (size_t)n0 * K + kt * BK;
#pragma unroll
    for (int c = 0; c < ACALLS; ++c)
      gload_lds16(Ag + (size_t)(c * 64 + w * 16 + sr) * K + sc,
                  Ab3 + buf * AE + (c * 64 + w * 16) * BK);
#pragma unroll
    for (int c = 0; c < BCALLS; ++c)
      gload_lds16(Bg + (size_t)(c * 64 + w * 16 + sr) * K + sc,
                  Bb3 + buf * BE + (c * 64 + w * 16) * BK);
  };

  f32x16 acc[AM][BN] = {};
  // prologue: stage k=0,1; leave k=1 in flight (counted)
  stage(0, 0);
  stage(1, 1);
  if constexpr (INF == 4) asm volatile("s_waitcnt vmcnt(4)" ::: "memory");
  else                    asm volatile("s_waitcnt vmcnt(2)" ::: "memory");
  __builtin_amdgcn_sched_barrier(0);
  __builtin_amdgcn_s_barrier();
  __builtin_amdgcn_sched_barrier(0);

  int kb = 0, kb2 = 2;
  for (int k = 0; k < 32; ++k) {
    const bool pre = (k + 2 < 32);
    if (pre) stage(k + 2, kb2);
    bf16x8 af[AM][2], bfr[BN][2];
#pragma unroll
    for (int am = 0; am < AM; ++am)
#pragma unroll
      for (int t = 0; t < 2; ++t)
        af[am][t] = *reinterpret_cast<const bf16x8*>(
            Ab3 + kb * AE + (wm + am * 32 + l31) * BK + ((t * 16 + hh * 8) ^ rswz));
#pragma unroll
    for (int bn = 0; bn < BN; ++bn)
#pragma unroll
      for (int t = 0; t < 2; ++t)
        bfr[bn][t] = *reinterpret_cast<const bf16x8*>(
            Bb3 + kb * BE + (wn + bn * 32 + l31) * BK + ((t * 16 + hh * 8) ^ rswz));
#pragma unroll
    for (int t = 0; t < 2; ++t)
#pragma unroll
      for (int am = 0; am < AM; ++am)
#pragma unroll
        for (int bn = 0; bn < BN; ++bn)
          acc[am][bn] = __builtin_amdgcn_mfma_f32_32x32x16_bf16(af[am][t], bfr[bn][t],
                                                               acc[am][bn], 0, 0, 0);
    if (k < 31) {
      if (pre) {
        if constexpr (INF == 4) asm volatile("s_waitcnt vmcnt(4)" ::: "memory");
        else                    asm volatile("s_waitcnt vmcnt(2)" ::: "memory");
      } else {
        asm volatile("s_waitcnt vmcnt(0)" ::: "memory");
      }
      asm volatile("s_waitcnt lgkmcnt(0)" ::: "memory");
      __builtin_amdgcn_sched_barrier(0);
      __builtin_amdgcn_s_barrier();
      __builtin_amdgcn_sched_barrier(0);
    }
    kb = (kb == 2) ? 0 : kb + 1;
    kb2 = (kb2 == 2) ? 0 : kb2 + 1;
  }

#pragma unroll
  for (int am = 0; am < AM; ++am)
#pragma unroll
    for (int bn = 0; bn < BN; ++bn)
#pragma unroll
      for (int r = 0; r < 16; ++r) {
        int m = m0 + wm + am * 32 + (r & 3) + 8 * (r >> 2) + 4 * hh;
        int n = n0 + wn + bn * 32 + l31;
        float v = acc[am][bn][r];
        if (MODE == 0) {
          bf16* dst = rt == 0 ? q_out : (rt == 1 ? k_out : v_out);
          int h = n >> 6, d = n & 63;
          int b = m >> 11, s = m & 2047;
          dst[(((size_t)b * H_ + h) * S_ + s) * DK + d] = (bf16)v;
        } else {
          c_out[(size_t)m * D_ + n] = v;
        }
      }
}

// ---------------- RoPE (vectorized; Q scaled by log2(e)/sqrt(dk) for exp2 softmax) -------
__global__ __launch_bounds__(256) void rope_kernel(bf16* __restrict__ Q, bf16* __restrict__ K) {
  const int NG = 32 * 2048 * 8;
  int idx = blockIdx.x * 256 + threadIdx.x;
  bf16* X = Q;
  float sc = 0.18033688f;  // 0.125 * log2(e)
  if (idx >= NG) { X = K; idx -= NG; sc = 1.0f; }
  int g = idx & 7;
  int s = (idx >> 3) & 2047;
  int bh = idx >> 14;
  size_t off = ((size_t)bh * S_ + s) * DK + g * 8;
  bf16x8 v = *reinterpret_cast<const bf16x8*>(X + off);
  bf16x8 o;
  const float c0 = -0.4152410118609203f;  // -log2(10000)/32
  float fs = (float)s;
#pragma unroll
  for (int p = 0; p < 4; ++p) {
    int i = g * 4 + p;
    float ang = fs * exp2f((float)i * c0);
    float sn = __sinf(ang), cs = __cosf(ang);
    float x1 = (float)v[2 * p], x2 = (float)v[2 * p + 1];
    o[2 * p]     = (bf16)((x1 * cs - x2 * sn) * sc);
    o[2 * p + 1] = (bf16)((x1 * sn + x2 * cs) * sc);
  }
  *reinterpret_cast<bf16x8*>(X + off) = o;
}

// ---------------- causal flash attention (exact round-17/20 kernel: 47.6us) --------------
__global__ __launch_bounds__(256, 4) void attn_kernel(
    const bf16* __restrict__ Q, const bf16* __restrict__ K, const bf16* __restrict__ V,
    bf16* __restrict__ O) {
  __shared__ __align__(16) char smem[40960];
  bf16* K3 = (bf16*)smem;
  bf16* Vt2 = (bf16*)smem + 12288;
  float* MG = (float*)smem;
  const int tid = threadIdx.x;
  const int w = tid >> 6, l = tid & 63;
  const int ql = l & 31, h = l >> 5;
  const int kh = w >> 1, qh = w & 1;
  const int bid = blockIdx.x;
  const int u = (bid >> 5) & 7;
  const int j = bid >> 8;
  const int qt = (j == 0) ? u : (j == 1) ? 31 - u : (j == 2) ? u + 8 : 23 - u;
  const int bh = bid & 31;
  const size_t base = (size_t)bh * S_ * DK;

  const size_t qrow = base + (size_t)(qt * 64 + qh * 32 + ql) * DK;
  bf16x8 qf[4];
#pragma unroll
  for (int t = 0; t < 4; ++t)
    qf[t] = *reinterpret_cast<const bf16x8*>(Q + qrow + t * 16 + h * 8);

  float l_run = 0.f;
  f32x16 o0 = {}, o1 = {};

  auto stageK = [&](int kt, int buf) {
#pragma unroll
    for (int c = 0; c < 2; ++c) {
      int row = c * 32 + w * 8 + (l >> 3);
      int col = ((l & 7) * 8) ^ ((row & 7) * 8);
      gload_lds16(K + base + (size_t)(kt * 64 + row) * DK + col,
                  K3 + buf * 4096 + c * 2048 + w * 512);
    }
  };
  auto loadV = [&](int kt, bf16x8 (&pv)[2]) {
    const bf16* vp = V + base + (size_t)(kt * 64 + l) * DK + w * 16;
    pv[0] = *reinterpret_cast<const bf16x8*>(vp);
    pv[1] = *reinterpret_cast<const bf16x8*>(vp + 8);
  };
  auto writeV = [&](int vb, const bf16x8 (&pv)[2]) {
    bf16* Vt = Vt2 + vb * 4096;
#pragma unroll
    for (int j2 = 0; j2 < 8; ++j2) {
      Vt[(w * 16 + j2) * 64 + (l ^ (j2 * 8))] = pv[0][j2];
      Vt[(w * 16 + 8 + j2) * 64 + (l ^ (j2 * 8))] = pv[1][j2];
    }
  };

  // prologue
  {
    bf16x8 pv[2];
    loadV(0, pv);
    stageK(0, 0);
    if (qt >= 1) stageK(1, 1);
    writeV(0, pv);
    if (qt >= 1) {
      asm volatile("s_waitcnt vmcnt(2)" ::: "memory");
    } else {
      asm volatile("s_waitcnt vmcnt(0)" ::: "memory");
    }
    asm volatile("s_waitcnt lgkmcnt(0)" ::: "memory");
    __builtin_amdgcn_sched_barrier(0);
    __builtin_amdgcn_s_barrier();
    __builtin_amdgcn_sched_barrier(0);
  }

  const int swzd = (ql & 7) * 8;
  const int keyA = kh * 32 + ql;
  const int limq = qh * 32 + ql;
  bf16x8 pvv[2];
  int kb = 0, kb2 = 2;

  for (int kt = 0; kt <= qt; ++kt) {
    const int vb = kt & 1;
    const bool pre = kt < qt;
    const bool pre2 = kt + 2 <= qt;
    const bool lastt = (kt == qt);
    const bool skipw = lastt && (kh == 1) && (qh == 0);
    if (pre) loadV(kt + 1, pvv);
    if (pre2) stageK(kt + 2, kb2);
    if (!skipw) {
      f32x16 ss = {};
      __builtin_amdgcn_s_setprio(1);
#pragma unroll
      for (int t = 0; t < 4; ++t) {
        bf16x8 kf = *reinterpret_cast<const bf16x8*>(
            K3 + kb * 4096 + keyA * 64 + ((t * 16 + h * 8) ^ ((keyA & 7) * 8)));
        ss = __builtin_amdgcn_mfma_f32_32x32x16_bf16(kf, qf[t], ss, 0, 0, 0);
      }
      __builtin_amdgcn_s_setprio(0);
      if (lastt) {
#pragma unroll
        for (int r = 0; r < 16; ++r) {
          int kl = kh * 32 + (r & 3) + 8 * (r >> 2) + 4 * h;
          if (kl > limq) ss[r] = -INFINITY;
        }
      }
      float t0 = 0.f, t1 = 0.f, t2 = 0.f, t3 = 0.f;
#pragma unroll
      for (int r = 0; r < 16; r += 4) {
        float p0 = exp2f(ss[r]);
        float p1 = exp2f(ss[r + 1]);
        float p2 = exp2f(ss[r + 2]);
        float p3 = exp2f(ss[r + 3]);
        ss[r] = p0; ss[r + 1] = p1; ss[r + 2] = p2; ss[r + 3] = p3;
        t0 += p0; t1 += p1; t2 += p2; t3 += p3;
      }
      l_run += (t0 + t1) + (t2 + t3);
      uint32_t Wq_[4][2];
#pragma unroll
      for (int g = 0; g < 4; ++g) {
        Wq_[g][0] = pkbf(ss[4 * g + 0], ss[4 * g + 1]);
        Wq_[g][1] = pkbf(ss[4 * g + 2], ss[4 * g + 3]);
      }
      __builtin_amdgcn_s_setprio(1);
#pragma unroll
      for (int ks = 0; ks < 2; ++ks) {
        uint32_t a0 = Wq_[2 * ks][0], a1 = Wq_[2 * ks][1];
        uint32_t b0 = Wq_[2 * ks + 1][0], b1 = Wq_[2 * ks + 1][1];
        uint32_t sxa0 = (uint32_t)__shfl_xor((int)a0, 32);
        uint32_t sxa1 = (uint32_t)__shfl_xor((int)a1, 32);
        uint32_t sxb0 = (uint32_t)__shfl_xor((int)b0, 32);
        uint32_t sxb1 = (uint32_t)__shfl_xor((int)b1, 32);
        union { uint32_t u[4]; bf16x8 v; } pa;
        pa.u[0] = h ? sxb0 : a0;
        pa.u[1] = h ? sxb1 : a1;
        pa.u[2] = h ? b0 : sxa0;
        pa.u[3] = h ? b1 : sxa1;
        int col = (kh * 32 + ks * 16 + h * 8) ^ swzd;
        const bf16* Vt = Vt2 + vb * 4096;
        bf16x8 v0 = *reinterpret_cast<const bf16x8*>(&Vt[ql * 64 + col]);
        bf16x8 v1 = *reinterpret_cast<const bf16x8*>(&Vt[(32 + ql) * 64 + col]);
        o0 = __builtin_amdgcn_mfma_f32_32x32x16_bf16(pa.v, v0, o0, 0, 0, 0);
        o1 = __builtin_amdgcn_mfma_f32_32x32x16_bf16(pa.v, v1, o1, 0, 0, 0);
      }
      __builtin_amdgcn_s_setprio(0);
    }
    if (pre) writeV(vb ^ 1, pvv);
    asm volatile("s_waitcnt vmcnt(2)" ::: "memory");
    asm volatile("s_waitcnt lgkmcnt(0)" ::: "memory");
    __builtin_amdgcn_sched_barrier(0);
    __builtin_amdgcn_s_barrier();
    __builtin_amdgcn_sched_barrier(0);
    kb = (kb == 2) ? 0 : kb + 1;
    kb2 = (kb2 == 2) ? 0 : kb2 + 1;
  }

  l_run += __shfl_xor(l_run, 32);
  __syncthreads();
  if (kh == 1) {
    int off = (qh * 64 + l) * 33;
    MG[off] = l_run;
#pragma unroll
    for (int r = 0; r < 16; ++r) {
      MG[off + 1 + r] = o0[r];
      MG[off + 17 + r] = o1[r];
    }
  }
  __syncthreads();
  if (kh == 0) {
    int off = (qh * 64 + l) * 33;
    float inv = 1.0f / (l_run + MG[off]);
    const int b = bh >> 4, hd = bh & 15;
#pragma unroll
    for (int r = 0; r < 16; ++r) {
      int rowl = (r & 3) + 8 * (r >> 2) + 4 * h;
      float invr = __shfl(inv, rowl);
      int qr = qt * 64 + qh * 32 + rowl;
      size_t ooff = ((size_t)b * S_ + qr) * D_ + hd * 64;
      O[ooff + ql] = (bf16)((o0[r] + MG[off + 1 + r]) * invr);
      O[ooff + 32 + ql] = (bf16)((o1[r] + MG[off + 17 + r]) * invr);
    }
  }
}

extern "C" void kernel_launch(void* const* d_in, const int* in_sizes, int n_in,
                              void* d_out, int out_size, void* d_ws, size_t ws_size,
                              hipStream_t stream) {
  const float* x  = (const float*)d_in[0];
  const float* Wq = (const float*)d_in[1];
  const float* Wk = (const float*)d_in[2];
  const float* Wv = (const float*)d_in[3];
  const float* Wo = (const float*)d_in[4];
  float* out = (float*)d_out;
  char* ws = (char*)d_ws;

  bf16* xb  = (bf16*)(ws + ((size_t)0 << 20));
  bf16* wqb = (bf16*)(ws + ((size_t)8 << 20));
  bf16* wkb = (bf16*)(ws + ((size_t)10 << 20));
  bf16* wvb = (bf16*)(ws + ((size_t)12 << 20));
  bf16* wob = (bf16*)(ws + ((size_t)14 << 20));
  bf16* Qb  = (bf16*)(ws + ((size_t)16 << 20));
  bf16* Kb  = (bf16*)(ws + ((size_t)24 << 20));
  bf16* Vb  = (bf16*)(ws + ((size_t)32 << 20));
  bf16* Ob  = (bf16*)(ws + ((size_t)40 << 20));

  cvt_all_kernel<<<8192, 256, 0, stream>>>(x, Wq, Wk, Wv, Wo, xb, wqb, wkb, wvb, wob);
  gemm_kernel<0><<<768, 256, 0, stream>>>(xb, wqb, wkb, wvb, Qb, Kb, Vb, nullptr);
  rope_kernel<<<4096, 256, 0, stream>>>(Qb, Kb);
  attn_kernel<<<1024, 256, 0, stream>>>(Qb, Kb, Vb, Ob);
  gemm_kernel<1><<<1024, 256, 0, stream>>>(Ob, wob, nullptr, nullptr, nullptr, nullptr,
                                           nullptr, out);
}

// Round 22
// 104.775 us; speedup vs baseline: 1.0953x; 1.0953x over previous
//
#include <hip/hip_runtime.h>
#include <hip/hip_bf16.h>
#include <stdint.h>

typedef __bf16 bf16;
typedef __bf16 bf16x8 __attribute__((ext_vector_type(8)));
typedef float f32x4 __attribute__((ext_vector_type(4)));
typedef float f32x16 __attribute__((ext_vector_type(16)));

#define B_ 2
#define S_ 2048
#define D_ 1024
#define H_ 16
#define DK 64
#define M_ 4096

__device__ __forceinline__ void gload_lds16(const void* g, void* l) {
  __builtin_amdgcn_global_load_lds(
      (const __attribute__((address_space(1))) uint32_t*)(uintptr_t)g,
      (__attribute__((address_space(3))) uint32_t*)(uintptr_t)l, 16, 0, 0);
}

__device__ __forceinline__ uint32_t pkbf(float a, float b) {
  union { uint32_t u; struct { bf16 x, y; } s; } r;
  r.s.x = (bf16)a; r.s.y = (bf16)b;
  return r.u;
}

// ---------------- f32 -> bf16 convert (all 5 tensors, one launch) ----------------
struct alignas(8) B4s { bf16 a, b, c, d; };

__global__ __launch_bounds__(256) void cvt_all_kernel(
    const float* __restrict__ x, const float* __restrict__ wq, const float* __restrict__ wk,
    const float* __restrict__ wv, const float* __restrict__ wo,
    bf16* __restrict__ xb, bf16* __restrict__ wqb, bf16* __restrict__ wkb,
    bf16* __restrict__ wvb, bf16* __restrict__ wob) {
  int i = blockIdx.x * 256 + threadIdx.x;  // float4 index
  const float* src;
  bf16* dst;
  int off;
  if (i < 1048576) { src = x; dst = xb; off = i; }
  else if (i < 1310720) { src = wq; dst = wqb; off = i - 1048576; }
  else if (i < 1572864) { src = wk; dst = wkb; off = i - 1310720; }
  else if (i < 1835008) { src = wv; dst = wvb; off = i - 1572864; }
  else { src = wo; dst = wob; off = i - 1835008; }
  float4 v = reinterpret_cast<const float4*>(src)[off];
  B4s o{(bf16)v.x, (bf16)v.y, (bf16)v.z, (bf16)v.w};
  reinterpret_cast<B4s*>(dst)[off] = o;
}

// ---------------- GEMM: C[m][n] = sum_k A[m][k] * W[n][k] ----------------
// 32x32x16 core + T2 XOR swizzle, BK=64, XCD-chunked 1D grid. (r20 proven config)
// MODE 0: 128x128 tiles, 768 blocks (3/CU), QKV fused -> head-major bf16.
// MODE 1: 64x64 tiles, 1024 blocks (4/CU).
template <int MODE>
__global__ __launch_bounds__(256, 3) void gemm_kernel(
    const bf16* __restrict__ A,
    const bf16* __restrict__ W0, const bf16* __restrict__ W1, const bf16* __restrict__ W2,
    bf16* __restrict__ q_out, bf16* __restrict__ k_out, bf16* __restrict__ v_out,
    float* __restrict__ c_out) {
  constexpr int BK = 64;
  constexpr int BM = (MODE == 0) ? 128 : 64;
  constexpr int BNR = (MODE == 0) ? 128 : 64;
  constexpr int AM = (MODE == 0) ? 2 : 1;
  constexpr int BN = (MODE == 0) ? 2 : 1;
  constexpr int NT = (MODE == 0) ? 24 : 16;
  constexpr int PERX = (MODE == 0) ? 96 : 128;
  __shared__ bf16 Alds[BM * BK];
  __shared__ bf16 Blds[BNR * BK];
  const int tid = threadIdx.x;
  const int w = tid >> 6, l = tid & 63;
  const int l31 = l & 31, hh = l >> 5;
  const int lin = (blockIdx.x & 7) * PERX + (blockIdx.x >> 3);
  const int m0 = (lin / NT) * BM;
  const int nt = lin % NT;
  const bf16* W;
  int n0;
  const int rt = (MODE == 0) ? (nt >> 3) : 0;
  if (MODE == 0) {
    W = rt == 0 ? W0 : (rt == 1 ? W1 : W2);
    n0 = (nt & 7) * 128;
  } else {
    W = W0;
    n0 = nt * 64;
  }
  const int K = 1024;
  const int wm = (MODE == 0) ? (w >> 1) * 64 : (w & 1) * 32;
  const int wn = (MODE == 0) ? (w & 1) * 64 : (w >> 1) * 32;
  const int srow = w * 8 + (l >> 3);
  const int scol = ((l & 7) * 8) ^ (((l >> 3) & 7) * 8);
  const int swz = (l & 7) * 8;
  f32x16 acc[AM][BN] = {};
  for (int k0 = 0; k0 < K; k0 += BK) {
    const bf16* Ab = A + (size_t)m0 * K + k0;
    const bf16* Bb = W + (size_t)n0 * K + k0;
#pragma unroll
    for (int c = 0; c < BM / 32; ++c)
      gload_lds16(Ab + (size_t)(c * 32 + srow) * K + scol, Alds + (c * 32 + w * 8) * BK);
#pragma unroll
    for (int c = 0; c < BNR / 32; ++c)
      gload_lds16(Bb + (size_t)(c * 32 + srow) * K + scol, Blds + (c * 32 + w * 8) * BK);
    __syncthreads();
    bf16x8 af[AM][4], bfr[BN][4];
#pragma unroll
    for (int am = 0; am < AM; ++am)
#pragma unroll
      for (int t = 0; t < 4; ++t)
        af[am][t] = *reinterpret_cast<const bf16x8*>(
            Alds + (wm + am * 32 + l31) * BK + ((t * 16 + hh * 8) ^ swz));
#pragma unroll
    for (int bn = 0; bn < BN; ++bn)
#pragma unroll
      for (int t = 0; t < 4; ++t)
        bfr[bn][t] = *reinterpret_cast<const bf16x8*>(
            Blds + (wn + bn * 32 + l31) * BK + ((t * 16 + hh * 8) ^ swz));
#pragma unroll
    for (int t = 0; t < 4; ++t)
#pragma unroll
      for (int am = 0; am < AM; ++am)
#pragma unroll
        for (int bn = 0; bn < BN; ++bn)
          acc[am][bn] = __builtin_amdgcn_mfma_f32_32x32x16_bf16(af[am][t], bfr[bn][t],
                                                               acc[am][bn], 0, 0, 0);
    __syncthreads();
  }
#pragma unroll
  for (int am = 0; am < AM; ++am)
#pragma unroll
    for (int bn = 0; bn < BN; ++bn)
#pragma unroll
      for (int r = 0; r < 16; ++r) {
        int m = m0 + wm + am * 32 + (r & 3) + 8 * (r >> 2) + 4 * hh;
        int n = n0 + wn + bn * 32 + l31;
        float v = acc[am][bn][r];
        if (MODE == 0) {
          bf16* dst = rt == 0 ? q_out : (rt == 1 ? k_out : v_out);
          int h = n >> 6, d = n & 63;
          int b = m >> 11, s = m & 2047;
          dst[(((size_t)b * H_ + h) * S_ + s) * DK + d] = (bf16)v;
        } else {
          c_out[(size_t)m * D_ + n] = v;
        }
      }
}

// ---------------- RoPE (vectorized; Q scaled by log2(e)/sqrt(dk) for exp2 softmax) -------
__global__ __launch_bounds__(256) void rope_kernel(bf16* __restrict__ Q, bf16* __restrict__ K) {
  const int NG = 32 * 2048 * 8;
  int idx = blockIdx.x * 256 + threadIdx.x;
  bf16* X = Q;
  float sc = 0.18033688f;  // 0.125 * log2(e)
  if (idx >= NG) { X = K; idx -= NG; sc = 1.0f; }
  int g = idx & 7;
  int s = (idx >> 3) & 2047;
  int bh = idx >> 14;
  size_t off = ((size_t)bh * S_ + s) * DK + g * 8;
  bf16x8 v = *reinterpret_cast<const bf16x8*>(X + off);
  bf16x8 o;
  const float c0 = -0.4152410118609203f;  // -log2(10000)/32
  float fs = (float)s;
#pragma unroll
  for (int p = 0; p < 4; ++p) {
    int i = g * 4 + p;
    float ang = fs * exp2f((float)i * c0);
    float sn = __sinf(ang), cs = __cosf(ang);
    float x1 = (float)v[2 * p], x2 = (float)v[2 * p + 1];
    o[2 * p]     = (bf16)((x1 * cs - x2 * sn) * sc);
    o[2 * p + 1] = (bf16)((x1 * sn + x2 * cs) * sc);
  }
  *reinterpret_cast<bf16x8*>(X + off) = o;
}

// ---------------- causal flash attention (exact round-17/20 kernel: 47.6us) --------------
__global__ __launch_bounds__(256, 4) void attn_kernel(
    const bf16* __restrict__ Q, const bf16* __restrict__ K, const bf16* __restrict__ V,
    bf16* __restrict__ O) {
  __shared__ __align__(16) char smem[40960];
  bf16* K3 = (bf16*)smem;
  bf16* Vt2 = (bf16*)smem + 12288;
  float* MG = (float*)smem;
  const int tid = threadIdx.x;
  const int w = tid >> 6, l = tid & 63;
  const int ql = l & 31, h = l >> 5;
  const int kh = w >> 1, qh = w & 1;
  const int bid = blockIdx.x;
  const int u = (bid >> 5) & 7;
  const int j = bid >> 8;
  const int qt = (j == 0) ? u : (j == 1) ? 31 - u : (j == 2) ? u + 8 : 23 - u;
  const int bh = bid & 31;
  const size_t base = (size_t)bh * S_ * DK;

  const size_t qrow = base + (size_t)(qt * 64 + qh * 32 + ql) * DK;
  bf16x8 qf[4];
#pragma unroll
  for (int t = 0; t < 4; ++t)
    qf[t] = *reinterpret_cast<const bf16x8*>(Q + qrow + t * 16 + h * 8);

  float l_run = 0.f;
  f32x16 o0 = {}, o1 = {};

  auto stageK = [&](int kt, int buf) {
#pragma unroll
    for (int c = 0; c < 2; ++c) {
      int row = c * 32 + w * 8 + (l >> 3);
      int col = ((l & 7) * 8) ^ ((row & 7) * 8);
      gload_lds16(K + base + (size_t)(kt * 64 + row) * DK + col,
                  K3 + buf * 4096 + c * 2048 + w * 512);
    }
  };
  auto loadV = [&](int kt, bf16x8 (&pv)[2]) {
    const bf16* vp = V + base + (size_t)(kt * 64 + l) * DK + w * 16;
    pv[0] = *reinterpret_cast<const bf16x8*>(vp);
    pv[1] = *reinterpret_cast<const bf16x8*>(vp + 8);
  };
  auto writeV = [&](int vb, const bf16x8 (&pv)[2]) {
    bf16* Vt = Vt2 + vb * 4096;
#pragma unroll
    for (int j2 = 0; j2 < 8; ++j2) {
      Vt[(w * 16 + j2) * 64 + (l ^ (j2 * 8))] = pv[0][j2];
      Vt[(w * 16 + 8 + j2) * 64 + (l ^ (j2 * 8))] = pv[1][j2];
    }
  };

  // prologue
  {
    bf16x8 pv[2];
    loadV(0, pv);
    stageK(0, 0);
    if (qt >= 1) stageK(1, 1);
    writeV(0, pv);
    if (qt >= 1) {
      asm volatile("s_waitcnt vmcnt(2)" ::: "memory");
    } else {
      asm volatile("s_waitcnt vmcnt(0)" ::: "memory");
    }
    asm volatile("s_waitcnt lgkmcnt(0)" ::: "memory");
    __builtin_amdgcn_sched_barrier(0);
    __builtin_amdgcn_s_barrier();
    __builtin_amdgcn_sched_barrier(0);
  }

  const int swzd = (ql & 7) * 8;
  const int keyA = kh * 32 + ql;
  const int limq = qh * 32 + ql;
  bf16x8 pvv[2];
  int kb = 0, kb2 = 2;

  for (int kt = 0; kt <= qt; ++kt) {
    const int vb = kt & 1;
    const bool pre = kt < qt;
    const bool pre2 = kt + 2 <= qt;
    const bool lastt = (kt == qt);
    const bool skipw = lastt && (kh == 1) && (qh == 0);
    if (pre) loadV(kt + 1, pvv);
    if (pre2) stageK(kt + 2, kb2);
    if (!skipw) {
      f32x16 ss = {};
      __builtin_amdgcn_s_setprio(1);
#pragma unroll
      for (int t = 0; t < 4; ++t) {
        bf16x8 kf = *reinterpret_cast<const bf16x8*>(
            K3 + kb * 4096 + keyA * 64 + ((t * 16 + h * 8) ^ ((keyA & 7) * 8)));
        ss = __builtin_amdgcn_mfma_f32_32x32x16_bf16(kf, qf[t], ss, 0, 0, 0);
      }
      __builtin_amdgcn_s_setprio(0);
      if (lastt) {
#pragma unroll
        for (int r = 0; r < 16; ++r) {
          int kl = kh * 32 + (r & 3) + 8 * (r >> 2) + 4 * h;
          if (kl > limq) ss[r] = -INFINITY;
        }
      }
      float t0 = 0.f, t1 = 0.f, t2 = 0.f, t3 = 0.f;
#pragma unroll
      for (int r = 0; r < 16; r += 4) {
        float p0 = exp2f(ss[r]);
        float p1 = exp2f(ss[r + 1]);
        float p2 = exp2f(ss[r + 2]);
        float p3 = exp2f(ss[r + 3]);
        ss[r] = p0; ss[r + 1] = p1; ss[r + 2] = p2; ss[r + 3] = p3;
        t0 += p0; t1 += p1; t2 += p2; t3 += p3;
      }
      l_run += (t0 + t1) + (t2 + t3);
      uint32_t Wq_[4][2];
#pragma unroll
      for (int g = 0; g < 4; ++g) {
        Wq_[g][0] = pkbf(ss[4 * g + 0], ss[4 * g + 1]);
        Wq_[g][1] = pkbf(ss[4 * g + 2], ss[4 * g + 3]);
      }
      __builtin_amdgcn_s_setprio(1);
#pragma unroll
      for (int ks = 0; ks < 2; ++ks) {
        uint32_t a0 = Wq_[2 * ks][0], a1 = Wq_[2 * ks][1];
        uint32_t b0 = Wq_[2 * ks + 1][0], b1 = Wq_[2 * ks + 1][1];
        uint32_t sxa0 = (uint32_t)__shfl_xor((int)a0, 32);
        uint32_t sxa1 = (uint32_t)__shfl_xor((int)a1, 32);
        uint32_t sxb0 = (uint32_t)__shfl_xor((int)b0, 32);
        uint32_t sxb1 = (uint32_t)__shfl_xor((int)b1, 32);
        union { uint32_t u[4]; bf16x8 v; } pa;
        pa.u[0] = h ? sxb0 : a0;
        pa.u[1] = h ? sxb1 : a1;
        pa.u[2] = h ? b0 : sxa0;
        pa.u[3] = h ? b1 : sxa1;
        int col = (kh * 32 + ks * 16 + h * 8) ^ swzd;
        const bf16* Vt = Vt2 + vb * 4096;
        bf16x8 v0 = *reinterpret_cast<const bf16x8*>(&Vt[ql * 64 + col]);
        bf16x8 v1 = *reinterpret_cast<const bf16x8*>(&Vt[(32 + ql) * 64 + col]);
        o0 = __builtin_amdgcn_mfma_f32_32x32x16_bf16(pa.v, v0, o0, 0, 0, 0);
        o1 = __builtin_amdgcn_mfma_f32_32x32x16_bf16(pa.v, v1, o1, 0, 0, 0);
      }
      __builtin_amdgcn_s_setprio(0);
    }
    if (pre) writeV(vb ^ 1, pvv);
    asm volatile("s_waitcnt vmcnt(2)" ::: "memory");
    asm volatile("s_waitcnt lgkmcnt(0)" ::: "memory");
    __builtin_amdgcn_sched_barrier(0);
    __builtin_amdgcn_s_barrier();
    __builtin_amdgcn_sched_barrier(0);
    kb = (kb == 2) ? 0 : kb + 1;
    kb2 = (kb2 == 2) ? 0 : kb2 + 1;
  }

  l_run += __shfl_xor(l_run, 32);
  __syncthreads();
  if (kh == 1) {
    int off = (qh * 64 + l) * 33;
    MG[off] = l_run;
#pragma unroll
    for (int r = 0; r < 16; ++r) {
      MG[off + 1 + r] = o0[r];
      MG[off + 17 + r] = o1[r];
    }
  }
  __syncthreads();
  if (kh == 0) {
    int off = (qh * 64 + l) * 33;
    float inv = 1.0f / (l_run + MG[off]);
    const int b = bh >> 4, hd = bh & 15;
#pragma unroll
    for (int r = 0; r < 16; ++r) {
      int rowl = (r & 3) + 8 * (r >> 2) + 4 * h;
      float invr = __shfl(inv, rowl);
      int qr = qt * 64 + qh * 32 + rowl;
      size_t ooff = ((size_t)b * S_ + qr) * D_ + hd * 64;
      O[ooff + ql] = (bf16)((o0[r] + MG[off + 1 + r]) * invr);
      O[ooff + 32 + ql] = (bf16)((o1[r] + MG[off + 17 + r]) * invr);
    }
  }
}

extern "C" void kernel_launch(void* const* d_in, const int* in_sizes, int n_in,
                              void* d_out, int out_size, void* d_ws, size_t ws_size,
                              hipStream_t stream) {
  const float* x  = (const float*)d_in[0];
  const float* Wq = (const float*)d_in[1];
  const float* Wk = (const float*)d_in[2];
  const float* Wv = (const float*)d_in[3];
  const float* Wo = (const float*)d_in[4];
  float* out = (float*)d_out;
  char* ws = (char*)d_ws;

  bf16* xb  = (bf16*)(ws + ((size_t)0 << 20));
  bf16* wqb = (bf16*)(ws + ((size_t)8 << 20));
  bf16* wkb = (bf16*)(ws + ((size_t)10 << 20));
  bf16* wvb = (bf16*)(ws + ((size_t)12 << 20));
  bf16* wob = (bf16*)(ws + ((size_t)14 << 20));
  bf16* Qb  = (bf16*)(ws + ((size_t)16 << 20));
  bf16* Kb  = (bf16*)(ws + ((size_t)24 << 20));
  bf16* Vb  = (bf16*)(ws + ((size_t)32 << 20));
  bf16* Ob  = (bf16*)(ws + ((size_t)40 << 20));

  cvt_all_kernel<<<8192, 256, 0, stream>>>(x, Wq, Wk, Wv, Wo, xb, wqb, wkb, wvb, wob);
  gemm_kernel<0><<<768, 256, 0, stream>>>(xb, wqb, wkb, wvb, Qb, Kb, Vb, nullptr);
  rope_kernel<<<4096, 256, 0, stream>>>(Qb, Kb);
  attn_kernel<<<1024, 256, 0, stream>>>(Qb, Kb, Vb, Ob);
  gemm_kernel<1><<<1024, 256, 0, stream>>>(Ob, wob, nullptr, nullptr, nullptr, nullptr,
                                           nullptr, out);
}